// Round 4
// baseline (323.248 us; speedup 1.0000x reference)
//
#include <hip/hip_runtime.h>
#include <hip/hip_bf16.h>
#include <math.h>

// GNN influence maximizer: 2x SAGEConv(mean) + MLP head.
// N=100000, E=640000, HID=128.
// R4: megaG phase-1 rebuilt as chunked prefetched CSR edge-walk (was: per-node
// serial dependent loads -> 101us latency-bound). Scan collapsed to 1 dispatch
// (redundant per-block prefix). hist/scatter 4 edges/thread for atomic ILP.
// 5 dispatches: memset | hist_pack | scan_scp | scatter | megaG.

#define N_NODES 100000
#define N_EDGES 640000
#define NBLK ((N_NODES + 255) / 256)     // 391
#define HB (N_EDGES / 4 / 256)           // 625 edge blocks (4 edges/thread)
#define ESTRIDE (N_EDGES / 4)            // 160000

typedef unsigned short u16;
typedef unsigned int   u32;
typedef __attribute__((ext_vector_type(8))) short frag_ab;  // 8 bf16
typedef __attribute__((ext_vector_type(4))) float frag_cd;  // 4 fp32

__device__ __forceinline__ float bf2f(u16 u) {
  union { u32 i; float f; } v; v.i = ((u32)u) << 16; return v.f;
}
__device__ __forceinline__ u16 f2bf(float f) {
  union { float f; u32 i; } v; v.f = f;
  u32 u = v.i;
  return (u16)((u + 0x7FFFu + ((u >> 16) & 1u)) >> 16);  // RNE
}

// ---- hist (blocks < HB, 4 edges/thread) + weight pack (remaining blocks)
__global__ void hist_pack(const int* __restrict__ ei, const float* __restrict__ x,
                          const float* __restrict__ W2l, const float* __restrict__ W2r,
                          const float* __restrict__ Wh1,
                          float* __restrict__ aggx, int* __restrict__ cnt,
                          u16* __restrict__ wt, u16* __restrict__ wh1t) {
  int b = blockIdx.x;
  if (b < HB) {
    int base = b * 256 + threadIdx.x;
    int s[4], d[4];
    float xv[4];
#pragma unroll
    for (int k = 0; k < 4; ++k) {
      s[k] = ei[base + k * ESTRIDE];
      d[k] = ei[N_EDGES + base + k * ESTRIDE];
    }
#pragma unroll
    for (int k = 0; k < 4; ++k) xv[k] = x[s[k]];
#pragma unroll
    for (int k = 0; k < 4; ++k) {
      atomicAdd(&aggx[d[k]], xv[k]);      // no return use -> fire-and-forget
      atomicAdd(&cnt[d[k]], 1);
    }
  } else {
    int idx = (b - HB) * 256 + threadIdx.x;
    if (idx < 32768) {                     // wt: 128 n x 256 k
      int k = idx >> 7, n = idx & 127;
      float v = (k < 128) ? W2l[k * 128 + n] : W2r[(k - 128) * 128 + n];
      wt[n * 256 + k] = f2bf(v);
    }
    int i2 = idx - 32768;
    if (i2 >= 0 && i2 < 8192) {            // wh1t: 64 n x 128 k
      int k = i2 >> 6, n = i2 & 63;
      wh1t[n * 128 + k] = f2bf(Wh1[k * 64 + n]);
    }
  }
}

// ---- single-dispatch scan (blocks < NBLK: redundant per-block prefix over cnt)
//      + scalar-pair table scp (blocks >= NBLK)
__global__ __launch_bounds__(256) void scan_scp(const int* __restrict__ cnt,
                                                const float* __restrict__ aggx,
                                                const float* __restrict__ x,
                                                int* __restrict__ rowptr,
                                                u32* __restrict__ scp) {
  int b = blockIdx.x, t = threadIdx.x;
  if (b < NBLK) {
    int lane = t & 63, w = t >> 6;
    // sum of all counts before this block (coalesced grid-stride, L2-hot)
    int pre = 0;
    for (int i = t; i < b * 256; i += 256) pre += cnt[i];
    int pr = pre;
#pragma unroll
    for (int off = 32; off > 0; off >>= 1) pr += __shfl_down(pr, off, 64);
    __shared__ int wsum[4], wscan[4];
    if (lane == 0) wsum[w] = pr;
    // local inclusive scan of this block's 256 counts
    int i = b * 256 + t;
    int v = (i < N_NODES) ? cnt[i] : 0;
    int xv = v;
#pragma unroll
    for (int off = 1; off < 64; off <<= 1) {
      int y = __shfl_up(xv, off, 64);
      if (lane >= off) xv += y;
    }
    if (lane == 63) wscan[w] = xv;
    __syncthreads();
    int blockpre = wsum[0] + wsum[1] + wsum[2] + wsum[3];
    int wo = 0;
    for (int k = 0; k < w; ++k) wo += wscan[k];
    if (i < N_NODES) rowptr[i] = blockpre + wo + xv - v;
    if (i == N_NODES - 1) rowptr[N_NODES] = blockpre + wo + xv;
  } else {
    int i = (b - NBLK) * 256 + t;
    if (i < N_NODES) {
      float m1 = aggx[i] / fmaxf((float)cnt[i], 1.0f);
      scp[i] = (u32)f2bf(m1) | ((u32)f2bf(x[i]) << 16);
    }
  }
}

// ---- scatter src indices into CSR col (4 edges/thread for atomic ILP)
__global__ void edge_scatter(const int* __restrict__ ei, const int* __restrict__ rowptr,
                             int* __restrict__ cursor, int* __restrict__ col) {
  int base = blockIdx.x * 256 + threadIdx.x;
  int s[4], d[4], p[4];
#pragma unroll
  for (int k = 0; k < 4; ++k) {
    s[k] = ei[base + k * ESTRIDE];
    d[k] = ei[N_EDGES + base + k * ESTRIDE];
  }
#pragma unroll
  for (int k = 0; k < 4; ++k) p[k] = atomicAdd(&cursor[d[k]], 1);
#pragma unroll
  for (int k = 0; k < 4; ++k) col[rowptr[d[k]] + p[k]] = s[k];
}

// ---- megaG: per block of 128 nodes:
//  phase1: chunked CSR edge-walk -> mean2 tile in LDS (bf16, XOR-swizzled)
//  phase2: h2 = [mean2 | h1(on-the-fly)] @ wt + b2  (MFMA)
//  phase3: z = relu(h2 @ wh1t + bh1); out = sigmoid(z @ Wh2 + bh2)
__global__ __launch_bounds__(256) void megaG(
    const u32* __restrict__ scp, const int* __restrict__ rowptr,
    const int* __restrict__ col, const u16* __restrict__ wt,
    const u16* __restrict__ wh1t, const float* __restrict__ W1l,
    const float* __restrict__ W1r, const float* __restrict__ b1,
    const float* __restrict__ b2, const float* __restrict__ bh1,
    const float* __restrict__ Wh2, const float* __restrict__ bh2,
    float* __restrict__ out) {
  __shared__ u16 tile[128 * 128];   // 32 KB; holds mean2, then h2, then z
  int tid = threadIdx.x;
  int w = tid >> 6, lane = tid & 63;
  int blockRow = blockIdx.x * 128;

  // ---- phase 1: wave walks its 32 nodes' contiguous CSR range in 64-edge chunks
  {
    float w1l0 = W1l[lane * 2], w1l1 = W1l[lane * 2 + 1];
    float w1r0 = W1r[lane * 2], w1r1 = W1r[lane * 2 + 1];
    float b10  = b1[lane * 2],  b11  = b1[lane * 2 + 1];
    int nbase = blockRow + w * 32;
    int rpi = nbase + ((lane < 33) ? lane : 32);
    int rp = rowptr[(rpi <= N_NODES) ? rpi : N_NODES];
    int beg32 = __shfl(rp, 0, 64), end32 = __shfl(rp, 32, 64);
    int nl = 0;
    int end_cur = __shfl(rp, 1, 64);
    int beg_cur = beg32;
    float a0 = 0.f, a1 = 0.f;
    // prefetch chunk 0
    int base = beg32;
    int m = end32 - base; if (m > 64) m = 64; if (m < 0) m = 0;
    int ci = (lane < m) ? col[base + lane] : 0;
    u32 pr = (lane < m) ? scp[ci] : 0;
    while (base < end32) {
      int nbase2 = base + 64;
      int mn = end32 - nbase2; if (mn > 64) mn = 64; if (mn < 0) mn = 0;
      int cn = (lane < mn) ? col[nbase2 + lane] : 0;
      u32 pn = (lane < mn) ? scp[cn] : 0;    // next chunk in flight during consume
      for (int j = 0; j < m; ++j) {
        int e = base + j;
        while (e == end_cur) {               // finalize node nl (wave-uniform)
          float inv = 1.0f / fmaxf((float)(end_cur - beg_cur), 1.0f);
          int row = w * 32 + nl;
          u32 vv = (u32)f2bf(a0 * inv) | ((u32)f2bf(a1 * inv) << 16);
          *(u32*)&tile[row * 128 + (((lane >> 2) ^ (row & 15)) << 3) + (lane & 3) * 2] = vv;
          a0 = a1 = 0.f; beg_cur = end_cur; ++nl;
          end_cur = __shfl(rp, nl + 1, 64);
        }
        u32 p = (u32)__shfl((int)pr, j, 64);
        float m1 = bf2f((u16)(p & 0xffff));
        float xx = bf2f((u16)(p >> 16));
        a0 += fmaxf(fmaf(m1, w1l0, fmaf(xx, w1r0, b10)), 0.f);
        a1 += fmaxf(fmaf(m1, w1l1, fmaf(xx, w1r1, b11)), 0.f);
      }
      base = nbase2; m = mn; pr = pn;
    }
    while (nl < 32) {                        // tail: remaining (possibly empty) nodes
      float inv = 1.0f / fmaxf((float)(end_cur - beg_cur), 1.0f);
      int row = w * 32 + nl;
      u32 vv = (u32)f2bf(a0 * inv) | ((u32)f2bf(a1 * inv) << 16);
      *(u32*)&tile[row * 128 + (((lane >> 2) ^ (row & 15)) << 3) + (lane & 3) * 2] = vv;
      a0 = a1 = 0.f; beg_cur = end_cur; ++nl;
      if (nl < 32) end_cur = __shfl(rp, nl + 1, 64);
    }
  }
  __syncthreads();

  // ---- phase 2: gemm1 over K=256 (ks<4: mean2 from LDS; ks>=4: h1 on the fly)
  int n15 = lane & 15, q = lane >> 4;
  frag_cd zero = {0.f, 0.f, 0.f, 0.f};
  frag_cd acc[2][8];
#pragma unroll
  for (int mt = 0; mt < 2; ++mt)
#pragma unroll
    for (int ct = 0; ct < 8; ++ct) acc[mt][ct] = zero;
  u32 pm[2];
#pragma unroll
  for (int mt = 0; mt < 2; ++mt) {
    int r = blockRow + w * 32 + mt * 16 + n15;
    pm[mt] = scp[(r < N_NODES) ? r : (N_NODES - 1)];
  }
#pragma unroll
  for (int ks = 0; ks < 8; ++ks) {
    frag_ab a[2];
    if (ks < 4) {
#pragma unroll
      for (int mt = 0; mt < 2; ++mt) {
        int rl = w * 32 + mt * 16 + n15;
        a[mt] = *(const frag_ab*)&tile[rl * 128 + (((ks * 4 + q) ^ n15) << 3)];
      }
    } else {
      float wf[8], rf[8], bf[8];
      int k0 = (ks - 4) * 32 + q * 8;
#pragma unroll
      for (int j = 0; j < 8; ++j) { wf[j] = W1l[k0 + j]; rf[j] = W1r[k0 + j]; bf[j] = b1[k0 + j]; }
#pragma unroll
      for (int mt = 0; mt < 2; ++mt) {
        float m1 = bf2f((u16)(pm[mt] & 0xffff));
        float xx = bf2f((u16)(pm[mt] >> 16));
        union { frag_ab f; short s[8]; } u;
#pragma unroll
        for (int j = 0; j < 8; ++j)
          u.s[j] = (short)f2bf(fmaxf(fmaf(m1, wf[j], fmaf(xx, rf[j], bf[j])), 0.f));
        a[mt] = u.f;
      }
    }
#pragma unroll
    for (int ct = 0; ct < 8; ++ct) {
      frag_ab b = *(const frag_ab*)&wt[(ct * 16 + n15) * 256 + ks * 32 + q * 8];
#pragma unroll
      for (int mt = 0; mt < 2; ++mt)
        acc[mt][ct] = __builtin_amdgcn_mfma_f32_16x16x32_bf16(a[mt], b, acc[mt][ct], 0, 0, 0);
    }
  }
  __syncthreads();   // all mean2 reads done; safe to overwrite tile with h2

  // epilogue: h2 -> tile (bf16, same swizzle). C/D layout: col=lane&15, row=q*4+r
#pragma unroll
  for (int ct = 0; ct < 8; ++ct) {
    int colg = ct * 16 + n15;
    float bias = b2[colg];
    int kb = colg >> 3;
#pragma unroll
    for (int mt = 0; mt < 2; ++mt) {
      int rbase = w * 32 + mt * 16 + q * 4;
#pragma unroll
      for (int r = 0; r < 4; ++r) {
        int rl = rbase + r;
        tile[rl * 128 + ((kb ^ (rl & 15)) << 3) + (colg & 7)] = f2bf(acc[mt][ct][r] + bias);
      }
    }
  }
  __syncthreads();

  // ---- phase 3: head. z = relu(h2 @ wh1t + bh1), K=128, 64 cols
  frag_cd zacc[2][4];
#pragma unroll
  for (int mt = 0; mt < 2; ++mt)
#pragma unroll
    for (int ct = 0; ct < 4; ++ct) zacc[mt][ct] = zero;
#pragma unroll
  for (int ks = 0; ks < 4; ++ks) {
    frag_ab a[2];
#pragma unroll
    for (int mt = 0; mt < 2; ++mt) {
      int rl = w * 32 + mt * 16 + n15;
      a[mt] = *(const frag_ab*)&tile[rl * 128 + (((ks * 4 + q) ^ n15) << 3)];
    }
#pragma unroll
    for (int ct = 0; ct < 4; ++ct) {
      frag_ab b = *(const frag_ab*)&wh1t[(ct * 16 + n15) * 128 + ks * 32 + q * 8];
#pragma unroll
      for (int mt = 0; mt < 2; ++mt)
        zacc[mt][ct] = __builtin_amdgcn_mfma_f32_16x16x32_bf16(a[mt], b, zacc[mt][ct], 0, 0, 0);
    }
  }
  __syncthreads();   // h2 reads done; overwrite tile with z (stride 68)
  u16* zt = tile;
#pragma unroll
  for (int ct = 0; ct < 4; ++ct) {
    int colg = ct * 16 + n15;
    float bias = bh1[colg];
#pragma unroll
    for (int mt = 0; mt < 2; ++mt) {
      int rbase = w * 32 + mt * 16 + q * 4;
#pragma unroll
      for (int r = 0; r < 4; ++r)
        zt[(rbase + r) * 68 + colg] = f2bf(fmaxf(zacc[mt][ct][r] + bias, 0.0f));
    }
  }
  __syncthreads();
  if (tid < 128) {
    int row = blockRow + tid;
    if (row < N_NODES) {
      float s = bh2[0];
#pragma unroll
      for (int k = 0; k < 64; ++k) s += bf2f(zt[tid * 68 + k]) * Wh2[k];
      out[row] = 1.0f / (1.0f + expf(-s));
    }
  }
}

extern "C" void kernel_launch(void* const* d_in, const int* in_sizes, int n_in,
                              void* d_out, int out_size, void* d_ws, size_t ws_size,
                              hipStream_t stream) {
  const float* x   = (const float*)d_in[0];
  const int*   ei  = (const int*)d_in[1];
  const float* W1l = (const float*)d_in[2];
  const float* W1r = (const float*)d_in[3];
  const float* b1  = (const float*)d_in[4];
  const float* W2l = (const float*)d_in[5];
  const float* W2r = (const float*)d_in[6];
  const float* b2  = (const float*)d_in[7];
  const float* Wh1 = (const float*)d_in[8];
  const float* bh1 = (const float*)d_in[9];
  const float* Wh2 = (const float*)d_in[10];
  const float* bh2 = (const float*)d_in[11];
  float* out = (float*)d_out;

  char* ws = (char*)d_ws;
  size_t off = 0;
  auto alloc = [&](size_t bytes) -> char* {
    char* p = ws + off;
    off += (bytes + 255) & ~(size_t)255;
    return p;
  };
  int*   cnt    = (int*)alloc(N_NODES * 4);
  float* aggx   = (float*)alloc(N_NODES * 4);
  int*   cursor = (int*)alloc(N_NODES * 4);
  size_t zero_bytes = off;                      // cnt+aggx+cursor contiguous
  int*   rowptr = (int*)alloc((N_NODES + 1) * 4);
  int*   col    = (int*)alloc(N_EDGES * 4);
  u32*   scp    = (u32*)alloc(N_NODES * 4);
  u16*   wt     = (u16*)alloc(65536);
  u16*   wh1t   = (u16*)alloc(16384);
  (void)ws_size; (void)in_sizes; (void)n_in; (void)out_size;

  hipMemsetAsync(ws, 0, zero_bytes, stream);
  hist_pack<<<HB + 160, 256, 0, stream>>>(ei, x, W2l, W2r, Wh1, aggx, cnt, wt, wh1t);
  scan_scp<<<NBLK * 2, 256, 0, stream>>>(cnt, aggx, x, rowptr, scp);
  edge_scatter<<<HB, 256, 0, stream>>>(ei, rowptr, cursor, col);
  megaG<<<(N_NODES + 127) / 128, 256, 0, stream>>>(scp, rowptr, col, wt, wh1t,
                                                   W1l, W1r, b1, b2, bh1, Wh2, bh2, out);
}

// Round 6
// 311.710 us; speedup vs baseline: 1.0370x; 1.0370x over previous
//
#include <hip/hip_runtime.h>
#include <hip/hip_bf16.h>
#include <math.h>

// GNN influence maximizer: 2x SAGEConv(mean) + MLP head.
// N=100000, E=640000, HID=128.
// R6: defensive rebuild of R5 (which faulted): no int4 casts on ei, rowptr
// boundaries staged in LDS instead of shuffles, no break-in-unroll. Kept:
// phase2/3 B-fragment hoists, 8-wide bpermute batches. New: edge rank stored
// during hist -> scatter is atomic-free.
// 5 dispatches: memset | hist_pack | scan_scp | scatter | megaG.

#define N_NODES 100000
#define N_EDGES 640000
#define NBLK ((N_NODES + 255) / 256)     // 391
#define HB (N_EDGES / 4 / 256)           // 625 edge blocks (4 consecutive edges/thread)

typedef unsigned short u16;
typedef unsigned int   u32;
typedef __attribute__((ext_vector_type(8))) short frag_ab;  // 8 bf16
typedef __attribute__((ext_vector_type(4))) float frag_cd;  // 4 fp32

__device__ __forceinline__ float bf2f(u16 u) {
  union { u32 i; float f; } v; v.i = ((u32)u) << 16; return v.f;
}
__device__ __forceinline__ u16 f2bf(float f) {
  union { float f; u32 i; } v; v.f = f;
  u32 u = v.i;
  return (u16)((u + 0x7FFFu + ((u >> 16) & 1u)) >> 16);  // RNE
}

// ---- hist (blocks < HB): 4 consecutive edges/thread; records per-edge rank
//      (atomic return) so scatter needs no atomics. + weight pack (rest).
__global__ void hist_pack(const int* __restrict__ ei, const float* __restrict__ x,
                          const float* __restrict__ W2l, const float* __restrict__ W2r,
                          const float* __restrict__ Wh1,
                          float* __restrict__ aggx, int* __restrict__ cnt,
                          int* __restrict__ rank,
                          u16* __restrict__ wt, u16* __restrict__ wh1t) {
  int b = blockIdx.x;
  if (b < HB) {
    int e0 = (b * 256 + threadIdx.x) * 4;
#pragma unroll
    for (int k = 0; k < 4; ++k) {
      int s = ei[e0 + k];
      int d = ei[N_EDGES + e0 + k];
      float xv = x[s];
      atomicAdd(&aggx[d], xv);
      rank[e0 + k] = atomicAdd(&cnt[d], 1);
    }
  } else {
    int idx = (b - HB) * 256 + threadIdx.x;
    if (idx < 32768) {                     // wt: 128 n x 256 k
      int k = idx >> 7, n = idx & 127;
      float v = (k < 128) ? W2l[k * 128 + n] : W2r[(k - 128) * 128 + n];
      wt[n * 256 + k] = f2bf(v);
    }
    int i2 = idx - 32768;
    if (i2 >= 0 && i2 < 8192) {            // wh1t: 64 n x 128 k
      int k = i2 >> 6, n = i2 & 63;
      wh1t[n * 128 + k] = f2bf(Wh1[k * 64 + n]);
    }
  }
}

// ---- single-dispatch scan (blocks < NBLK: redundant per-block prefix over cnt)
//      + scalar-pair table scp (blocks >= NBLK)
__global__ __launch_bounds__(256) void scan_scp(const int* __restrict__ cnt,
                                                const float* __restrict__ aggx,
                                                const float* __restrict__ x,
                                                int* __restrict__ rowptr,
                                                u32* __restrict__ scp) {
  int b = blockIdx.x, t = threadIdx.x;
  if (b < NBLK) {
    int lane = t & 63, w = t >> 6;
    int pre = 0;
    for (int i = t; i < b * 256; i += 256) pre += cnt[i];
    int pr = pre;
#pragma unroll
    for (int off = 32; off > 0; off >>= 1) pr += __shfl_down(pr, off, 64);
    __shared__ int wsum[4], wscan[4];
    if (lane == 0) wsum[w] = pr;
    int i = b * 256 + t;
    int v = (i < N_NODES) ? cnt[i] : 0;
    int xv = v;
#pragma unroll
    for (int off = 1; off < 64; off <<= 1) {
      int y = __shfl_up(xv, off, 64);
      if (lane >= off) xv += y;
    }
    if (lane == 63) wscan[w] = xv;
    __syncthreads();
    int blockpre = wsum[0] + wsum[1] + wsum[2] + wsum[3];
    int wo = 0;
    for (int k = 0; k < w; ++k) wo += wscan[k];
    if (i < N_NODES) rowptr[i] = blockpre + wo + xv - v;
    if (i == N_NODES - 1) rowptr[N_NODES] = blockpre + wo + xv;
  } else {
    int i = (b - NBLK) * 256 + t;
    if (i < N_NODES) {
      float m1 = aggx[i] / fmaxf((float)cnt[i], 1.0f);
      scp[i] = (u32)f2bf(m1) | ((u32)f2bf(x[i]) << 16);
    }
  }
}

// ---- scatter src indices into CSR col: atomic-free (uses precomputed rank)
__global__ void edge_scatter(const int* __restrict__ ei, const int* __restrict__ rowptr,
                             const int* __restrict__ rank, int* __restrict__ col) {
  int e0 = (blockIdx.x * 256 + threadIdx.x) * 4;
#pragma unroll
  for (int k = 0; k < 4; ++k) {
    int s = ei[e0 + k];
    int d = ei[N_EDGES + e0 + k];
    col[rowptr[d] + rank[e0 + k]] = s;
  }
}

// ---- megaG: per block of 128 nodes:
//  phase1: chunked CSR edge-walk (8-wide batched bpermute, LDS rowptr bounds)
//          -> mean2 tile in LDS (bf16, XOR-swizzled)
//  phase2: h2 = [mean2 | h1(on-the-fly)] @ wt + b2  (MFMA, B hoisted 8-wide)
//  phase3: z = relu(h2 @ wh1t + bh1); out = sigmoid(z @ Wh2 + bh2)
__global__ __launch_bounds__(256) void megaG(
    const u32* __restrict__ scp, const int* __restrict__ rowptr,
    const int* __restrict__ col, const u16* __restrict__ wt,
    const u16* __restrict__ wh1t, const float* __restrict__ W1l,
    const float* __restrict__ W1r, const float* __restrict__ b1,
    const float* __restrict__ b2, const float* __restrict__ bh1,
    const float* __restrict__ Wh2, const float* __restrict__ bh2,
    float* __restrict__ out) {
  __shared__ u16 tile[128 * 128];   // 32 KB; holds mean2, then h2, then z
  __shared__ int rps[4][34];        // per-wave rowptr slice [nbase .. nbase+32]
  int tid = threadIdx.x;
  int w = tid >> 6, lane = tid & 63;
  int blockRow = blockIdx.x * 128;

  // ---- phase 1
  {
    float w1l0 = W1l[lane * 2], w1l1 = W1l[lane * 2 + 1];
    float w1r0 = W1r[lane * 2], w1r1 = W1r[lane * 2 + 1];
    float b10  = b1[lane * 2],  b11  = b1[lane * 2 + 1];
    int nbase = blockRow + w * 32;
    if (lane < 33) {
      int rpi = nbase + lane;
      rps[w][lane] = rowptr[(rpi <= N_NODES) ? rpi : N_NODES];
    }
    // wave-local LDS: compiler inserts lgkm wait; no __syncthreads needed
    int beg32 = rps[w][0], end32 = rps[w][32];
    int nl = 0;
    int beg_cur = beg32, end_cur = rps[w][1];
    float a0 = 0.f, a1 = 0.f;
    int base = beg32;
    int m = end32 - base; if (m > 64) m = 64; if (m < 0) m = 0;
    u32 pr = 0;
    if (lane < m) pr = scp[col[base + lane]];
    while (base < end32) {
      int nb2 = base + 64;
      int mn = end32 - nb2; if (mn > 64) mn = 64; if (mn < 0) mn = 0;
      u32 pn = 0;
      if (lane < mn) pn = scp[col[nb2 + lane]];   // next chunk in flight
      for (int j = 0; j < m; j += 8) {
        u32 pb[8];
#pragma unroll
        for (int jj = 0; jj < 8; ++jj) {
          int sl = j + jj; sl = (sl < 63) ? sl : 63;
          pb[jj] = (u32)__shfl((int)pr, sl, 64);   // 8 bpermutes, 1 lgkm wait
        }
        int jmax = m - j; if (jmax > 8) jmax = 8;
        for (int jj = 0; jj < jmax; ++jj) {
          int e = base + j + jj;
          while (e == end_cur) {                   // finalize node nl (uniform)
            float inv = 1.0f / fmaxf((float)(end_cur - beg_cur), 1.0f);
            int row = w * 32 + nl;
            u32 vv = (u32)f2bf(a0 * inv) | ((u32)f2bf(a1 * inv) << 16);
            *(u32*)&tile[row * 128 + (((lane >> 2) ^ (row & 15)) << 3) + (lane & 3) * 2] = vv;
            a0 = a1 = 0.f; beg_cur = end_cur; ++nl;
            end_cur = rps[w][nl + 1];
          }
          float m1 = bf2f((u16)(pb[jj] & 0xffff));
          float xx = bf2f((u16)(pb[jj] >> 16));
          a0 += fmaxf(fmaf(m1, w1l0, fmaf(xx, w1r0, b10)), 0.f);
          a1 += fmaxf(fmaf(m1, w1l1, fmaf(xx, w1r1, b11)), 0.f);
        }
      }
      base = nb2; m = mn; pr = pn;
    }
    while (nl < 32) {                        // tail: remaining (empty) nodes
      float inv = 1.0f / fmaxf((float)(end_cur - beg_cur), 1.0f);
      int row = w * 32 + nl;
      u32 vv = (u32)f2bf(a0 * inv) | ((u32)f2bf(a1 * inv) << 16);
      *(u32*)&tile[row * 128 + (((lane >> 2) ^ (row & 15)) << 3) + (lane & 3) * 2] = vv;
      a0 = a1 = 0.f; beg_cur = end_cur; ++nl;
      if (nl < 32) end_cur = rps[w][nl + 1];
    }
  }
  __syncthreads();

  // ---- phase 2: gemm1 over K=256 (ks<4: mean2 from LDS; ks>=4: h1 on the fly)
  int n15 = lane & 15, q = lane >> 4;
  frag_cd zero = {0.f, 0.f, 0.f, 0.f};
  frag_cd acc[2][8];
#pragma unroll
  for (int mt = 0; mt < 2; ++mt)
#pragma unroll
    for (int ct = 0; ct < 8; ++ct) acc[mt][ct] = zero;
  u32 pm[2];
#pragma unroll
  for (int mt = 0; mt < 2; ++mt) {
    int r = blockRow + w * 32 + mt * 16 + n15;
    pm[mt] = scp[(r < N_NODES) ? r : (N_NODES - 1)];
  }
#pragma unroll
  for (int ks = 0; ks < 8; ++ks) {
    frag_ab bfr[8];   // 8 independent global loads in flight, then MFMA burst
#pragma unroll
    for (int ct = 0; ct < 8; ++ct)
      bfr[ct] = *(const frag_ab*)&wt[(ct * 16 + n15) * 256 + ks * 32 + q * 8];
    frag_ab a[2];
    if (ks < 4) {
#pragma unroll
      for (int mt = 0; mt < 2; ++mt) {
        int rl = w * 32 + mt * 16 + n15;
        a[mt] = *(const frag_ab*)&tile[rl * 128 + (((ks * 4 + q) ^ n15) << 3)];
      }
    } else {
      float wf[8], rf[8], bf[8];
      int k0 = (ks - 4) * 32 + q * 8;
#pragma unroll
      for (int j = 0; j < 8; ++j) { wf[j] = W1l[k0 + j]; rf[j] = W1r[k0 + j]; bf[j] = b1[k0 + j]; }
#pragma unroll
      for (int mt = 0; mt < 2; ++mt) {
        float m1 = bf2f((u16)(pm[mt] & 0xffff));
        float xx = bf2f((u16)(pm[mt] >> 16));
        union { frag_ab f; short s[8]; } u;
#pragma unroll
        for (int j = 0; j < 8; ++j)
          u.s[j] = (short)f2bf(fmaxf(fmaf(m1, wf[j], fmaf(xx, rf[j], bf[j])), 0.f));
        a[mt] = u.f;
      }
    }
#pragma unroll
    for (int ct = 0; ct < 8; ++ct)
#pragma unroll
      for (int mt = 0; mt < 2; ++mt)
        acc[mt][ct] = __builtin_amdgcn_mfma_f32_16x16x32_bf16(a[mt], bfr[ct], acc[mt][ct], 0, 0, 0);
  }
  __syncthreads();   // all mean2 reads done; safe to overwrite tile with h2

  // epilogue: h2 -> tile (bf16, same swizzle). C/D layout: col=lane&15, row=q*4+r
#pragma unroll
  for (int ct = 0; ct < 8; ++ct) {
    int colg = ct * 16 + n15;
    float bias = b2[colg];
    int kb = colg >> 3;
#pragma unroll
    for (int mt = 0; mt < 2; ++mt) {
      int rbase = w * 32 + mt * 16 + q * 4;
#pragma unroll
      for (int r = 0; r < 4; ++r) {
        int rl = rbase + r;
        tile[rl * 128 + ((kb ^ (rl & 15)) << 3) + (colg & 7)] = f2bf(acc[mt][ct][r] + bias);
      }
    }
  }
  __syncthreads();

  // ---- phase 3: head. z = relu(h2 @ wh1t + bh1), K=128, 64 cols
  frag_cd zacc[2][4];
#pragma unroll
  for (int mt = 0; mt < 2; ++mt)
#pragma unroll
    for (int ct = 0; ct < 4; ++ct) zacc[mt][ct] = zero;
#pragma unroll
  for (int ks = 0; ks < 4; ++ks) {
    frag_ab bfr[4];
#pragma unroll
    for (int ct = 0; ct < 4; ++ct)
      bfr[ct] = *(const frag_ab*)&wh1t[(ct * 16 + n15) * 128 + ks * 32 + q * 8];
    frag_ab a[2];
#pragma unroll
    for (int mt = 0; mt < 2; ++mt) {
      int rl = w * 32 + mt * 16 + n15;
      a[mt] = *(const frag_ab*)&tile[rl * 128 + (((ks * 4 + q) ^ n15) << 3)];
    }
#pragma unroll
    for (int ct = 0; ct < 4; ++ct)
#pragma unroll
      for (int mt = 0; mt < 2; ++mt)
        zacc[mt][ct] = __builtin_amdgcn_mfma_f32_16x16x32_bf16(a[mt], bfr[ct], zacc[mt][ct], 0, 0, 0);
  }
  __syncthreads();   // h2 reads done; overwrite tile with z (stride 68)
  u16* zt = tile;
#pragma unroll
  for (int ct = 0; ct < 4; ++ct) {
    int colg = ct * 16 + n15;
    float bias = bh1[colg];
#pragma unroll
    for (int mt = 0; mt < 2; ++mt) {
      int rbase = w * 32 + mt * 16 + q * 4;
#pragma unroll
      for (int r = 0; r < 4; ++r)
        zt[(rbase + r) * 68 + colg] = f2bf(fmaxf(zacc[mt][ct][r] + bias, 0.0f));
    }
  }
  __syncthreads();
  if (tid < 128) {
    int row = blockRow + tid;
    if (row < N_NODES) {
      float s = bh2[0];
#pragma unroll
      for (int k = 0; k < 64; ++k) s += bf2f(zt[tid * 68 + k]) * Wh2[k];
      out[row] = 1.0f / (1.0f + expf(-s));
    }
  }
}

extern "C" void kernel_launch(void* const* d_in, const int* in_sizes, int n_in,
                              void* d_out, int out_size, void* d_ws, size_t ws_size,
                              hipStream_t stream) {
  const float* x   = (const float*)d_in[0];
  const int*   ei  = (const int*)d_in[1];
  const float* W1l = (const float*)d_in[2];
  const float* W1r = (const float*)d_in[3];
  const float* b1  = (const float*)d_in[4];
  const float* W2l = (const float*)d_in[5];
  const float* W2r = (const float*)d_in[6];
  const float* b2  = (const float*)d_in[7];
  const float* Wh1 = (const float*)d_in[8];
  const float* bh1 = (const float*)d_in[9];
  const float* Wh2 = (const float*)d_in[10];
  const float* bh2 = (const float*)d_in[11];
  float* out = (float*)d_out;

  char* ws = (char*)d_ws;
  size_t off = 0;
  auto alloc = [&](size_t bytes) -> char* {
    char* p = ws + off;
    off += (bytes + 255) & ~(size_t)255;
    return p;
  };
  int*   cnt    = (int*)alloc(N_NODES * 4);
  float* aggx   = (float*)alloc(N_NODES * 4);
  size_t zero_bytes = off;                      // cnt+aggx contiguous
  int*   rowptr = (int*)alloc((N_NODES + 1) * 4);
  int*   col    = (int*)alloc(N_EDGES * 4);
  int*   rank   = (int*)alloc(N_EDGES * 4);
  u32*   scp    = (u32*)alloc(N_NODES * 4);
  u16*   wt     = (u16*)alloc(65536);
  u16*   wh1t   = (u16*)alloc(16384);
  (void)ws_size; (void)in_sizes; (void)n_in; (void)out_size;

  hipMemsetAsync(ws, 0, zero_bytes, stream);
  hist_pack<<<HB + 160, 256, 0, stream>>>(ei, x, W2l, W2r, Wh1, aggx, cnt, rank, wt, wh1t);
  scan_scp<<<NBLK * 2, 256, 0, stream>>>(cnt, aggx, x, rowptr, scp);
  edge_scatter<<<HB, 256, 0, stream>>>(ei, rowptr, rank, col);
  megaG<<<(N_NODES + 127) / 128, 256, 0, stream>>>(scp, rowptr, col, wt, wh1t,
                                                   W1l, W1r, b1, b2, bh1, Wh2, bh2, out);
}

// Round 7
// 276.970 us; speedup vs baseline: 1.1671x; 1.1254x over previous
//
#include <hip/hip_runtime.h>
#include <hip/hip_bf16.h>
#include <math.h>

// GNN influence maximizer: 2x SAGEConv(mean) + MLP head.
// N=100000, E=640000, HID=128.
// R7: phase-1 broadcast path rebuilt LDS-free. Per-edge scp broadcast via
// v_readlane (SALU) with unrolled constant lane index; (m1,x) unpacked with
// scalar shifts (bf16<<16 == fp32 bits); node boundaries kept in a VGPR and
// read via dynamic readlane. R6's per-edge ds_bpermute + rps LDS reads made
// all 12 waves/CU contend on the LDS pipe (~93% stall).
// 5 dispatches: memset | hist_pack | scan_scp | scatter | megaG.

#define N_NODES 100000
#define N_EDGES 640000
#define NBLK ((N_NODES + 255) / 256)     // 391
#define HB (N_EDGES / 4 / 256)           // 625 edge blocks (4 consecutive edges/thread)

typedef unsigned short u16;
typedef unsigned int   u32;
typedef __attribute__((ext_vector_type(8))) short frag_ab;  // 8 bf16
typedef __attribute__((ext_vector_type(4))) float frag_cd;  // 4 fp32

__device__ __forceinline__ float bf2f(u16 u) {
  union { u32 i; float f; } v; v.i = ((u32)u) << 16; return v.f;
}
__device__ __forceinline__ u16 f2bf(float f) {
  union { float f; u32 i; } v; v.f = f;
  u32 u = v.i;
  return (u16)((u + 0x7FFFu + ((u >> 16) & 1u)) >> 16);  // RNE
}
__device__ __forceinline__ float bits2f(u32 b) {
  union { u32 i; float f; } v; v.i = b; return v.f;
}

// ---- hist (blocks < HB): 4 consecutive edges/thread; records per-edge rank
//      (atomic return) so scatter needs no atomics. + weight pack (rest).
__global__ void hist_pack(const int* __restrict__ ei, const float* __restrict__ x,
                          const float* __restrict__ W2l, const float* __restrict__ W2r,
                          const float* __restrict__ Wh1,
                          float* __restrict__ aggx, int* __restrict__ cnt,
                          int* __restrict__ rank,
                          u16* __restrict__ wt, u16* __restrict__ wh1t) {
  int b = blockIdx.x;
  if (b < HB) {
    int e0 = (b * 256 + threadIdx.x) * 4;
#pragma unroll
    for (int k = 0; k < 4; ++k) {
      int s = ei[e0 + k];
      int d = ei[N_EDGES + e0 + k];
      float xv = x[s];
      atomicAdd(&aggx[d], xv);
      rank[e0 + k] = atomicAdd(&cnt[d], 1);
    }
  } else {
    int idx = (b - HB) * 256 + threadIdx.x;
    if (idx < 32768) {                     // wt: 128 n x 256 k
      int k = idx >> 7, n = idx & 127;
      float v = (k < 128) ? W2l[k * 128 + n] : W2r[(k - 128) * 128 + n];
      wt[n * 256 + k] = f2bf(v);
    }
    int i2 = idx - 32768;
    if (i2 >= 0 && i2 < 8192) {            // wh1t: 64 n x 128 k
      int k = i2 >> 6, n = i2 & 63;
      wh1t[n * 128 + k] = f2bf(Wh1[k * 64 + n]);
    }
  }
}

// ---- single-dispatch scan (blocks < NBLK: redundant per-block prefix over cnt)
//      + scalar-pair table scp (blocks >= NBLK)
__global__ __launch_bounds__(256) void scan_scp(const int* __restrict__ cnt,
                                                const float* __restrict__ aggx,
                                                const float* __restrict__ x,
                                                int* __restrict__ rowptr,
                                                u32* __restrict__ scp) {
  int b = blockIdx.x, t = threadIdx.x;
  if (b < NBLK) {
    int lane = t & 63, w = t >> 6;
    int pre = 0;
    for (int i = t; i < b * 256; i += 256) pre += cnt[i];
    int pr = pre;
#pragma unroll
    for (int off = 32; off > 0; off >>= 1) pr += __shfl_down(pr, off, 64);
    __shared__ int wsum[4], wscan[4];
    if (lane == 0) wsum[w] = pr;
    int i = b * 256 + t;
    int v = (i < N_NODES) ? cnt[i] : 0;
    int xv = v;
#pragma unroll
    for (int off = 1; off < 64; off <<= 1) {
      int y = __shfl_up(xv, off, 64);
      if (lane >= off) xv += y;
    }
    if (lane == 63) wscan[w] = xv;
    __syncthreads();
    int blockpre = wsum[0] + wsum[1] + wsum[2] + wsum[3];
    int wo = 0;
    for (int k = 0; k < w; ++k) wo += wscan[k];
    if (i < N_NODES) rowptr[i] = blockpre + wo + xv - v;
    if (i == N_NODES - 1) rowptr[N_NODES] = blockpre + wo + xv;
  } else {
    int i = (b - NBLK) * 256 + t;
    if (i < N_NODES) {
      float m1 = aggx[i] / fmaxf((float)cnt[i], 1.0f);
      scp[i] = (u32)f2bf(m1) | ((u32)f2bf(x[i]) << 16);
    }
  }
}

// ---- scatter src indices into CSR col: atomic-free (uses precomputed rank)
__global__ void edge_scatter(const int* __restrict__ ei, const int* __restrict__ rowptr,
                             const int* __restrict__ rank, int* __restrict__ col) {
  int e0 = (blockIdx.x * 256 + threadIdx.x) * 4;
#pragma unroll
  for (int k = 0; k < 4; ++k) {
    int s = ei[e0 + k];
    int d = ei[N_EDGES + e0 + k];
    col[rowptr[d] + rank[e0 + k]] = s;
  }
}

// ---- megaG: per block of 128 nodes:
//  phase1: LDS-free chunked CSR edge-walk (readlane broadcast) -> mean2 tile
//  phase2: h2 = [mean2 | h1(on-the-fly)] @ wt + b2  (MFMA, B hoisted 8-wide)
//  phase3: z = relu(h2 @ wh1t + bh1); out = sigmoid(z @ Wh2 + bh2)
__global__ __launch_bounds__(256) void megaG(
    const u32* __restrict__ scp, const int* __restrict__ rowptr,
    const int* __restrict__ col, const u16* __restrict__ wt,
    const u16* __restrict__ wh1t, const float* __restrict__ W1l,
    const float* __restrict__ W1r, const float* __restrict__ b1,
    const float* __restrict__ b2, const float* __restrict__ bh1,
    const float* __restrict__ Wh2, const float* __restrict__ bh2,
    float* __restrict__ out) {
  __shared__ u16 tile[128 * 128];   // 32 KB; holds mean2, then h2, then z
  int tid = threadIdx.x;
  int w = tid >> 6, lane = tid & 63;
  int blockRow = blockIdx.x * 128;

  // ---- phase 1: wave walks its 32 nodes' CSR range in 64-edge chunks.
  // Broadcasts are SALU readlanes (no LDS). rpv: lane l (<=32) holds
  // rowptr[nbase+l]; boundaries fetched by dynamic-index readlane.
  {
    float w1l0 = W1l[lane * 2], w1l1 = W1l[lane * 2 + 1];
    float w1r0 = W1r[lane * 2], w1r1 = W1r[lane * 2 + 1];
    float b10  = b1[lane * 2],  b11  = b1[lane * 2 + 1];
    int nbase = blockRow + w * 32;
    int rpi = nbase + ((lane < 33) ? lane : 32);
    int rpv = rowptr[(rpi <= N_NODES) ? rpi : N_NODES];
    int beg32 = __builtin_amdgcn_readlane(rpv, 0);
    int end32 = __builtin_amdgcn_readlane(rpv, 32);
    int nl = 0;
    int beg_cur = beg32;
    int end_cur = __builtin_amdgcn_readlane(rpv, 1);
    float a0 = 0.f, a1 = 0.f;
    int base = beg32;
    int m = end32 - base; if (m > 64) m = 64; if (m < 0) m = 0;
    u32 pr = 0;
    if (lane < m) pr = scp[col[base + lane]];
    while (base < end32) {
      int nb2 = base + 64;
      int mn = end32 - nb2; if (mn > 64) mn = 64; if (mn < 0) mn = 0;
      u32 pn = 0;
      if (lane < mn) pn = scp[col[nb2 + lane]];   // next chunk in flight
#pragma unroll
      for (int j = 0; j < 64; ++j) {
        if (j < m) {                               // wave-uniform guard
          u32 p = (u32)__builtin_amdgcn_readlane((int)pr, j);  // SALU broadcast
          int e = base + j;
          while (e == end_cur) {                   // finalize node nl (uniform)
            float inv = 1.0f / fmaxf((float)(end_cur - beg_cur), 1.0f);
            int row = w * 32 + nl;
            u32 vv = (u32)f2bf(a0 * inv) | ((u32)f2bf(a1 * inv) << 16);
            *(u32*)&tile[row * 128 + (((lane >> 2) ^ (row & 15)) << 3) + (lane & 3) * 2] = vv;
            a0 = a1 = 0.f; beg_cur = end_cur; ++nl;
            end_cur = __builtin_amdgcn_readlane(rpv, nl + 1);
          }
          float m1 = bits2f(p << 16);              // bf16 low half -> fp32
          float xx = bits2f(p & 0xffff0000u);      // bf16 high half -> fp32
          a0 += fmaxf(fmaf(m1, w1l0, fmaf(xx, w1r0, b10)), 0.f);
          a1 += fmaxf(fmaf(m1, w1l1, fmaf(xx, w1r1, b11)), 0.f);
        }
      }
      base = nb2; m = mn; pr = pn;
    }
    while (nl < 32) {                        // tail: remaining (possibly empty) nodes
      float inv = 1.0f / fmaxf((float)(end_cur - beg_cur), 1.0f);
      int row = w * 32 + nl;
      u32 vv = (u32)f2bf(a0 * inv) | ((u32)f2bf(a1 * inv) << 16);
      *(u32*)&tile[row * 128 + (((lane >> 2) ^ (row & 15)) << 3) + (lane & 3) * 2] = vv;
      a0 = a1 = 0.f; beg_cur = end_cur; ++nl;
      if (nl < 32) end_cur = __builtin_amdgcn_readlane(rpv, nl + 1);
    }
  }
  __syncthreads();

  // ---- phase 2: gemm1 over K=256 (ks<4: mean2 from LDS; ks>=4: h1 on the fly)
  int n15 = lane & 15, q = lane >> 4;
  frag_cd zero = {0.f, 0.f, 0.f, 0.f};
  frag_cd acc[2][8];
#pragma unroll
  for (int mt = 0; mt < 2; ++mt)
#pragma unroll
    for (int ct = 0; ct < 8; ++ct) acc[mt][ct] = zero;
  u32 pm[2];
#pragma unroll
  for (int mt = 0; mt < 2; ++mt) {
    int r = blockRow + w * 32 + mt * 16 + n15;
    pm[mt] = scp[(r < N_NODES) ? r : (N_NODES - 1)];
  }
#pragma unroll
  for (int ks = 0; ks < 8; ++ks) {
    frag_ab bfr[8];   // 8 independent global loads in flight, then MFMA burst
#pragma unroll
    for (int ct = 0; ct < 8; ++ct)
      bfr[ct] = *(const frag_ab*)&wt[(ct * 16 + n15) * 256 + ks * 32 + q * 8];
    frag_ab a[2];
    if (ks < 4) {
#pragma unroll
      for (int mt = 0; mt < 2; ++mt) {
        int rl = w * 32 + mt * 16 + n15;
        a[mt] = *(const frag_ab*)&tile[rl * 128 + (((ks * 4 + q) ^ n15) << 3)];
      }
    } else {
      float wf[8], rf[8], bf[8];
      int k0 = (ks - 4) * 32 + q * 8;
#pragma unroll
      for (int j = 0; j < 8; ++j) { wf[j] = W1l[k0 + j]; rf[j] = W1r[k0 + j]; bf[j] = b1[k0 + j]; }
#pragma unroll
      for (int mt = 0; mt < 2; ++mt) {
        float m1 = bf2f((u16)(pm[mt] & 0xffff));
        float xx = bf2f((u16)(pm[mt] >> 16));
        union { frag_ab f; short s[8]; } u;
#pragma unroll
        for (int j = 0; j < 8; ++j)
          u.s[j] = (short)f2bf(fmaxf(fmaf(m1, wf[j], fmaf(xx, rf[j], bf[j])), 0.f));
        a[mt] = u.f;
      }
    }
#pragma unroll
    for (int ct = 0; ct < 8; ++ct)
#pragma unroll
      for (int mt = 0; mt < 2; ++mt)
        acc[mt][ct] = __builtin_amdgcn_mfma_f32_16x16x32_bf16(a[mt], bfr[ct], acc[mt][ct], 0, 0, 0);
  }
  __syncthreads();   // all mean2 reads done; safe to overwrite tile with h2

  // epilogue: h2 -> tile (bf16, same swizzle). C/D layout: col=lane&15, row=q*4+r
#pragma unroll
  for (int ct = 0; ct < 8; ++ct) {
    int colg = ct * 16 + n15;
    float bias = b2[colg];
    int kb = colg >> 3;
#pragma unroll
    for (int mt = 0; mt < 2; ++mt) {
      int rbase = w * 32 + mt * 16 + q * 4;
#pragma unroll
      for (int r = 0; r < 4; ++r) {
        int rl = rbase + r;
        tile[rl * 128 + ((kb ^ (rl & 15)) << 3) + (colg & 7)] = f2bf(acc[mt][ct][r] + bias);
      }
    }
  }
  __syncthreads();

  // ---- phase 3: head. z = relu(h2 @ wh1t + bh1), K=128, 64 cols
  frag_cd zacc[2][4];
#pragma unroll
  for (int mt = 0; mt < 2; ++mt)
#pragma unroll
    for (int ct = 0; ct < 4; ++ct) zacc[mt][ct] = zero;
#pragma unroll
  for (int ks = 0; ks < 4; ++ks) {
    frag_ab bfr[4];
#pragma unroll
    for (int ct = 0; ct < 4; ++ct)
      bfr[ct] = *(const frag_ab*)&wh1t[(ct * 16 + n15) * 128 + ks * 32 + q * 8];
    frag_ab a[2];
#pragma unroll
    for (int mt = 0; mt < 2; ++mt) {
      int rl = w * 32 + mt * 16 + n15;
      a[mt] = *(const frag_ab*)&tile[rl * 128 + (((ks * 4 + q) ^ n15) << 3)];
    }
#pragma unroll
    for (int ct = 0; ct < 4; ++ct)
#pragma unroll
      for (int mt = 0; mt < 2; ++mt)
        zacc[mt][ct] = __builtin_amdgcn_mfma_f32_16x16x32_bf16(a[mt], bfr[ct], zacc[mt][ct], 0, 0, 0);
  }
  __syncthreads();   // h2 reads done; overwrite tile with z (stride 68)
  u16* zt = tile;
#pragma unroll
  for (int ct = 0; ct < 4; ++ct) {
    int colg = ct * 16 + n15;
    float bias = bh1[colg];
#pragma unroll
    for (int mt = 0; mt < 2; ++mt) {
      int rbase = w * 32 + mt * 16 + q * 4;
#pragma unroll
      for (int r = 0; r < 4; ++r)
        zt[(rbase + r) * 68 + colg] = f2bf(fmaxf(zacc[mt][ct][r] + bias, 0.0f));
    }
  }
  __syncthreads();
  if (tid < 128) {
    int row = blockRow + tid;
    if (row < N_NODES) {
      float s = bh2[0];
#pragma unroll
      for (int k = 0; k < 64; ++k) s += bf2f(zt[tid * 68 + k]) * Wh2[k];
      out[row] = 1.0f / (1.0f + expf(-s));
    }
  }
}

extern "C" void kernel_launch(void* const* d_in, const int* in_sizes, int n_in,
                              void* d_out, int out_size, void* d_ws, size_t ws_size,
                              hipStream_t stream) {
  const float* x   = (const float*)d_in[0];
  const int*   ei  = (const int*)d_in[1];
  const float* W1l = (const float*)d_in[2];
  const float* W1r = (const float*)d_in[3];
  const float* b1  = (const float*)d_in[4];
  const float* W2l = (const float*)d_in[5];
  const float* W2r = (const float*)d_in[6];
  const float* b2  = (const float*)d_in[7];
  const float* Wh1 = (const float*)d_in[8];
  const float* bh1 = (const float*)d_in[9];
  const float* Wh2 = (const float*)d_in[10];
  const float* bh2 = (const float*)d_in[11];
  float* out = (float*)d_out;

  char* ws = (char*)d_ws;
  size_t off = 0;
  auto alloc = [&](size_t bytes) -> char* {
    char* p = ws + off;
    off += (bytes + 255) & ~(size_t)255;
    return p;
  };
  int*   cnt    = (int*)alloc(N_NODES * 4);
  float* aggx   = (float*)alloc(N_NODES * 4);
  size_t zero_bytes = off;                      // cnt+aggx contiguous
  int*   rowptr = (int*)alloc((N_NODES + 1) * 4);
  int*   col    = (int*)alloc(N_EDGES * 4);
  int*   rank   = (int*)alloc(N_EDGES * 4);
  u32*   scp    = (u32*)alloc(N_NODES * 4);
  u16*   wt     = (u16*)alloc(65536);
  u16*   wh1t   = (u16*)alloc(16384);
  (void)ws_size; (void)in_sizes; (void)n_in; (void)out_size;

  hipMemsetAsync(ws, 0, zero_bytes, stream);
  hist_pack<<<HB + 160, 256, 0, stream>>>(ei, x, W2l, W2r, Wh1, aggx, cnt, rank, wt, wh1t);
  scan_scp<<<NBLK * 2, 256, 0, stream>>>(cnt, aggx, x, rowptr, scp);
  edge_scatter<<<HB, 256, 0, stream>>>(ei, rowptr, rank, col);
  megaG<<<(N_NODES + 127) / 128, 256, 0, stream>>>(scp, rowptr, col, wt, wh1t,
                                                   W1l, W1r, b1, b2, bh1, Wh2, bh2, out);
}